// Round 1
// baseline (227.545 us; speedup 1.0000x reference)
//
#include <hip/hip_runtime.h>
#include <hip/hip_bf16.h>

#define NTOK 2048
#define DMODEL 768
#define DFF 3072
#define NEXP 8

typedef short bf16x8 __attribute__((ext_vector_type(8)));
typedef float f32x4 __attribute__((ext_vector_type(4)));

// ---------------- router: logits (fp64 acc) + argmax + bf16 cast of x ----------------
__global__ __launch_bounds__(256) void k_router(
    const float* __restrict__ x, const float* __restrict__ rw,
    const float* __restrict__ rb, __hip_bfloat16* __restrict__ xbf,
    int* __restrict__ eidx, int* __restrict__ cnt) {
  int tok = (blockIdx.x * blockDim.x + threadIdx.x) >> 6;
  int lane = threadIdx.x & 63;
  if (tok >= NTOK) return;
  const float* xr = x + (size_t)tok * DMODEL;
  double acc[NEXP];
#pragma unroll
  for (int e = 0; e < NEXP; e++) acc[e] = 0.0;
  for (int d0 = 0; d0 < DMODEL; d0 += 64) {
    float v = xr[d0 + lane];
    xbf[(size_t)tok * DMODEL + d0 + lane] = __float2bfloat16(v);
    const float* wrow = rw + (size_t)(d0 + lane) * NEXP;
#pragma unroll
    for (int e = 0; e < NEXP; e++) acc[e] += (double)v * (double)wrow[e];
  }
#pragma unroll
  for (int e = 0; e < NEXP; e++) {
    double a = acc[e];
#pragma unroll
    for (int s = 32; s > 0; s >>= 1) a += __shfl_xor(a, s);
    acc[e] = a;
  }
  if (lane == 0) {
    int best = 0;
    double bv = acc[0] + (double)rb[0];
#pragma unroll
    for (int e = 1; e < NEXP; e++) {
      double v = acc[e] + (double)rb[e];
      if (v > bv) { bv = v; best = e; }  // strict > keeps first max (jnp.argmax)
    }
    eidx[tok] = best;
    atomicAdd(&cnt[best], 1);
  }
}

// ---------------- prefix scan over 8 experts + load-balance loss ----------------
__global__ void k_scan(const int* __restrict__ cnt, int* __restrict__ off,
                       int* __restrict__ cur, float* __restrict__ loss) {
  if (threadIdx.x == 0) {
    int s = 0;
    float l = 0.f;
    for (int e = 0; e < NEXP; e++) {
      off[e] = s;
      cur[e] = s;
      s += cnt[e];
      float u = (float)cnt[e] / (float)NTOK - 1.0f / (float)NEXP;
      l += u * u;
    }
    *loss = l / (float)NEXP;
  }
}

// ---------------- build per-expert packed token lists ----------------
__global__ __launch_bounds__(256) void k_build(const int* __restrict__ eidx,
                                               int* __restrict__ cur,
                                               int* __restrict__ list) {
  int t = blockIdx.x * blockDim.x + threadIdx.x;
  if (t < NTOK) {
    int e = eidx[t];
    int p = atomicAdd(&cur[e], 1);
    list[p] = t;
  }
}

// ---------------- grouped GEMM, 128x128 tile, BK=32, 4 waves, mfma 16x16x32 bf16 ----
// A: bf16 packed rows [NTOK][K] (gathered via list if GATHER_A)
// Bw: fp32 [NEXP][K][N]  (k-major -> transposed into LDS as [n][k] bf16)
// RELU_BF16: epilogue relu + bf16 store to packed h; else fp32 store (+scatter by list)
template <int K, int N, bool RELU_BF16, bool GATHER_A, bool SCATTER_C>
__global__ __launch_bounds__(256) void k_gemm(
    const __hip_bfloat16* __restrict__ A, const float* __restrict__ Bw,
    const float* __restrict__ bias, void* __restrict__ Cout,
    const int* __restrict__ cnt, const int* __restrict__ off,
    const int* __restrict__ list) {
  const int e = blockIdx.z;
  const int ce = cnt[e];
  const int m0 = blockIdx.y * 128;
  if (m0 >= ce) return;
  const int oe = off[e];
  const int n0 = blockIdx.x * 128;

  __shared__ __hip_bfloat16 Asm[128][32];  // [m][k]
  __shared__ __hip_bfloat16 Bsm[128][32];  // [n][k] (transposed)

  const int tid = threadIdx.x;

  // A staging: 2 threads per row (16 bf16 each)
  const int ra = tid >> 1;
  const int ha = (tid & 1) * 16;
  size_t arow;
  {
    int mr = m0 + ra;
    int src;
    if (GATHER_A) {
      src = (mr < ce) ? list[oe + mr] : 0;  // padded rows: any valid row (results discarded)
    } else {
      int p = oe + mr;
      src = (p < NTOK) ? p : (NTOK - 1);
    }
    arow = (size_t)src * K;
  }

  // B staging: thread -> k-row (tid>>3), 16-col chunk ((tid&7)*16); coalesced global read
  const int rbk = tid >> 3;
  const int nb = (tid & 7) * 16;
  const float* bsrc0 = Bw + ((size_t)e * K + rbk) * N + n0 + nb;

  const int w = tid >> 6;
  const int lane = tid & 63;
  const int wr = (w >> 1) * 64;
  const int wc = (w & 1) * 64;
  const int fr = lane & 15;        // frag row (A) / col (B)
  const int fk = (lane >> 4) * 8;  // frag k offset

  f32x4 acc[4][4] = {};

  for (int k0 = 0; k0 < K; k0 += 32) {
    __syncthreads();
    {  // A tile -> LDS (already bf16, contiguous 16B writes)
      const __hip_bfloat16* s = A + arow + k0 + ha;
      int4 v0 = *(const int4*)(s);
      int4 v1 = *(const int4*)(s + 8);
      *(int4*)(&Asm[ra][ha]) = v0;
      *(int4*)(&Asm[ra][ha + 8]) = v1;
    }
    {  // B tile -> LDS transposed + fp32->bf16
      const float* s = bsrc0 + (size_t)k0 * N;
      float4 f0 = *(const float4*)(s);
      float4 f1 = *(const float4*)(s + 4);
      float4 f2 = *(const float4*)(s + 8);
      float4 f3 = *(const float4*)(s + 12);
      __hip_bfloat16* dst = &Bsm[nb][0] + rbk;  // Bsm[nb+i][rbk] = dst[i*32]
      dst[0 * 32] = __float2bfloat16(f0.x);
      dst[1 * 32] = __float2bfloat16(f0.y);
      dst[2 * 32] = __float2bfloat16(f0.z);
      dst[3 * 32] = __float2bfloat16(f0.w);
      dst[4 * 32] = __float2bfloat16(f1.x);
      dst[5 * 32] = __float2bfloat16(f1.y);
      dst[6 * 32] = __float2bfloat16(f1.z);
      dst[7 * 32] = __float2bfloat16(f1.w);
      dst[8 * 32] = __float2bfloat16(f2.x);
      dst[9 * 32] = __float2bfloat16(f2.y);
      dst[10 * 32] = __float2bfloat16(f2.z);
      dst[11 * 32] = __float2bfloat16(f2.w);
      dst[12 * 32] = __float2bfloat16(f3.x);
      dst[13 * 32] = __float2bfloat16(f3.y);
      dst[14 * 32] = __float2bfloat16(f3.z);
      dst[15 * 32] = __float2bfloat16(f3.w);
    }
    __syncthreads();

    bf16x8 fa[4], fb[4];
#pragma unroll
    for (int mf = 0; mf < 4; mf++)
      fa[mf] = *(const bf16x8*)(&Asm[wr + mf * 16 + fr][fk]);
#pragma unroll
    for (int nf = 0; nf < 4; nf++)
      fb[nf] = *(const bf16x8*)(&Bsm[wc + nf * 16 + fr][fk]);
#pragma unroll
    for (int mf = 0; mf < 4; mf++)
#pragma unroll
      for (int nf = 0; nf < 4; nf++)
        acc[mf][nf] =
            __builtin_amdgcn_mfma_f32_16x16x32_bf16(fa[mf], fb[nf], acc[mf][nf], 0, 0, 0);
  }

  // epilogue: C/D layout col = lane&15, row = (lane>>4)*4 + j
#pragma unroll
  for (int mf = 0; mf < 4; mf++) {
#pragma unroll
    for (int j = 0; j < 4; j++) {
      const int mloc = m0 + wr + mf * 16 + (lane >> 4) * 4 + j;
      if (mloc >= ce) continue;
      if (RELU_BF16) {
        __hip_bfloat16* C = (__hip_bfloat16*)Cout;
        size_t row = (size_t)(oe + mloc) * N;
        const float* bi = bias + (size_t)e * N;
#pragma unroll
        for (int nf = 0; nf < 4; nf++) {
          int nn = n0 + wc + nf * 16 + fr;
          float v = acc[mf][nf][j] + bi[nn];
          C[row + nn] = __float2bfloat16(v > 0.f ? v : 0.f);
        }
      } else {
        float* C = (float*)Cout;
        int tok = SCATTER_C ? list[oe + mloc] : (oe + mloc);
        size_t row = (size_t)tok * N;
        const float* bi = bias + (size_t)e * N;
#pragma unroll
        for (int nf = 0; nf < 4; nf++) {
          int nn = n0 + wc + nf * 16 + fr;
          C[row + nn] = acc[mf][nf][j] + bi[nn];
        }
      }
    }
  }
}

// ws layout (bytes):
//   [0,32)      cnt[8]
//   [32,64)     off[8]
//   [64,96)     cur[8]
//   [128,8320)  eidx[2048]
//   [8320,16512) list[2048]
//   [32768, +3145728)   xbf  bf16 [2048][768]
//   [4194304, +12582912) h    bf16 [2048][3072]   (total < 17 MB)
extern "C" void kernel_launch(void* const* d_in, const int* in_sizes, int n_in,
                              void* d_out, int out_size, void* d_ws, size_t ws_size,
                              hipStream_t stream) {
  const float* x = (const float*)d_in[0];
  const float* rw = (const float*)d_in[1];
  const float* rb = (const float*)d_in[2];
  const float* w1 = (const float*)d_in[3];
  const float* b1 = (const float*)d_in[4];
  const float* w2 = (const float*)d_in[5];
  const float* b2 = (const float*)d_in[6];
  float* out = (float*)d_out;

  char* ws = (char*)d_ws;
  int* cnt = (int*)(ws + 0);
  int* off = (int*)(ws + 32);
  int* cur = (int*)(ws + 64);
  int* eidx = (int*)(ws + 128);
  int* list = (int*)(ws + 8320);
  __hip_bfloat16* xbf = (__hip_bfloat16*)(ws + 32768);
  __hip_bfloat16* h = (__hip_bfloat16*)(ws + 4194304);

  float* loss = out + (size_t)2 * 1024 * 768;

  (void)hipMemsetAsync(cnt, 0, 96, stream);
  k_router<<<512, 256, 0, stream>>>(x, rw, rb, xbf, eidx, cnt);
  k_scan<<<1, 64, 0, stream>>>(cnt, off, cur, loss);
  k_build<<<8, 256, 0, stream>>>(eidx, cur, list);
  // FFN1: h = relu(x_bf @ w1[e] + b1[e])  -> packed bf16
  k_gemm<DMODEL, DFF, true, true, false>
      <<<dim3(DFF / 128, 16, NEXP), 256, 0, stream>>>(xbf, w1, b1, h, cnt, off, list);
  // FFN2: out[tok] = h @ w2[e] + b2[e]    -> scattered fp32
  k_gemm<DFF, DMODEL, false, false, true>
      <<<dim3(DMODEL / 128, 16, NEXP), 256, 0, stream>>>(h, w2, b2, out, cnt, off, list);
}